// Round 3
// baseline (100.081 us; speedup 1.0000x reference)
//
#include <hip/hip_runtime.h>

#define NROWS 256
#define ROWLEN 65536
#define TPB 1024
#define LOSS_IDX ((size_t)NROWS * (size_t)ROWLEN)

// XOR swizzle: bijective involution within each 1024-float block; spreads the
// stride-2C chunked accesses across banks. Applied to EVERY access of buf[].
__device__ __forceinline__ int SW(int i) { return i ^ ((i >> 5) & 31); }

__device__ __forceinline__ float sigm(float z) { return 1.0f / (1.0f + __expf(-z)); }

__device__ __forceinline__ float hthr(float v, float a, float bp, float bm) {
    return v * (sigm(a * (v - bp)) + sigm(-a * (v + bm)));
}

// Intra-wave "barrier": compiler fence + lgkmcnt drain. Valid only when the
// producing and consuming lanes are in the SAME wave (deep levels, tid<64).
__device__ __forceinline__ void wave_sync() {
    __builtin_amdgcn_wave_barrier();
    __threadfence_block();
    __builtin_amdgcn_wave_barrier();
}

__device__ __forceinline__ void ldf_fwd(const float* sc, const float* rec, int lvl,
                                        float* sf, float* wv) {
    #pragma unroll
    for (int i = 0; i < 8; ++i) sf[i] = sc[lvl * 8 + i];
    #pragma unroll
    for (int i = 0; i < 8; ++i) {
        float r = rec[lvl * 8 + 7 - i];
        wv[i] = (i & 1) ? -r : r;            // _compute_wavelet
    }
}

__device__ __forceinline__ void ldf_rec(const float* sc, const float* rec, int lvl,
                                        float* sf, float* ws) {
    #pragma unroll
    for (int i = 0; i < 8; ++i) sf[i] = sc[lvl * 8 + i];
    #pragma unroll
    for (int i = 0; i < 8; ++i) {
        float r = rec[lvl * 8 + 7 - i];
        ws[i] = (i & 1) ? r : -r;            // _compute_wavelet_synthesis
    }
}

// Forward lifting level, fully in LDS: approx buf[0:2M) -> approx buf[0:M),
// thresholded detail -> buf[M:2M). Register-staged halo breaks the WAR.
template<int C, bool WAVE>
__device__ __forceinline__ void fwd_level(float* __restrict__ buf, int M, int tid,
                                          const float* sf, const float* wv,
                                          float a, float bp, float bm, float& loss)
{
    const int c0 = tid * C;          // C == M / nthreads exactly -> all active
    float ev[C + 7], od[C + 7];
    #pragma unroll
    for (int j = 0; j < C + 7; ++j) {
        int m = (c0 - 7 + j) & (M - 1);
        ev[j] = buf[SW(2 * m)];
        od[j] = buf[SW(2 * m + 1)];
    }
    if constexpr (WAVE) wave_sync(); else __syncthreads();
    #pragma unroll
    for (int j = 0; j < C; ++j) {
        float ao = 0.f, ae = 0.f;
        #pragma unroll
        for (int k = 0; k < 8; ++k) {
            ao = fmaf(wv[k], ev[j + 7 - k], ao);   // conv(even, wav)[n]
            ae = fmaf(sf[k], od[j + 7 - k], ae);   // conv(odd, scaling)[n]
        }
        int n = c0 + j;
        buf[SW(n)] = od[j + 7] - ao;               // odd_u -> next approx
        float d = hthr(ev[j + 7] - ae, a, bp, bm); // threshold(even_u)
        loss += fabsf(d);
        buf[SW(M + n)] = d;                        // det_l nests at [M:2M)
    }
    if constexpr (WAVE) wave_sync(); else __syncthreads();
}

// Inverse lifting level, fully in LDS: approx buf[0:M) + det buf[M:2M)
// -> buf[0:2M) interleaved [even_rest, odd_rest]. Register-staged.
template<int C, bool WAVE>
__device__ __forceinline__ void rec_level(float* __restrict__ buf, int M, int tid,
                                          const float* sf, const float* ws)
{
    const int c0 = tid * C;
    float od[C + 7], dt[C + 7];
    #pragma unroll
    for (int j = 0; j < C + 7; ++j) {
        int m = (c0 + j) & (M - 1);
        od[j] = buf[SW(m)];
        dt[j] = buf[SW(M + m)];
    }
    if constexpr (WAVE) wave_sync(); else __syncthreads();
    #pragma unroll
    for (int j = 0; j < C; ++j) {
        float ae = 0.f, ao = 0.f;
        #pragma unroll
        for (int k = 0; k < 8; ++k) {
            ae = fmaf(sf[k], od[j + k], ae);   // corr(odd, scaling)[n]
            ao = fmaf(ws[k], dt[j + k], ao);   // corr(even, ws)[n]
        }
        int n = c0 + j;
        buf[SW(2 * n)]     = dt[j] + ae;       // even_rest
        buf[SW(2 * n + 1)] = od[j] + ao;       // odd_rest
    }
    if constexpr (WAVE) wave_sync(); else __syncthreads();
}

// __launch_bounds__(1024, 4): 16 waves/block = 4 waves/SIMD minimum anyway
// (LDS forces 1 block/CU), so grant the register allocator the full
// 512/4 = 128 VGPR budget instead of the generic 64 -> no scratch spills.
__global__ __launch_bounds__(TPB, 4) void wavelet_vcycle_kernel(
    const float* __restrict__ x, const float* __restrict__ scaling,
    const float* __restrict__ scaling_rec, const float* __restrict__ pa,
    const float* __restrict__ pbp, const float* __restrict__ pbm,
    float* __restrict__ out)
{
    extern __shared__ float buf[];                 // 32768 floats = 128 KiB
    __shared__ float wb[16][8];                    // wave-boundary det0 halo
    __shared__ float lossbuf[16];
    const int tid  = threadIdx.x;
    const int lane = tid & 63;
    const int wv_id = tid >> 6;
    const int row = blockIdx.x;
    const float* xr = x + (size_t)row * ROWLEN;
    float* outr = out + (size_t)row * ROWLEN;
    const float a = pa[0], bp = pbp[0], bm = pbm[0];
    float loss = 0.f;
    float sf[8], wv8[8];
    float det0[32];                                // level-0 details live here

    // ---------- forward level 0: x (global, reg-staged float4) -> approx_1 (LDS)
    //            det_0 -> registers. Two passes of C=16. ----------
    ldf_fwd(scaling, scaling_rec, 0, sf, wv8);
    #pragma unroll
    for (int p = 0; p < 2; ++p) {
        const int c0 = tid * 32 + p * 16;
        float ev[24], od[24];
        #pragma unroll
        for (int i = 0; i < 12; ++i) {
            int mm = (c0 - 8 + 2 * i) & 32767;     // mm even -> no intra-vec wrap
            float4 v = *(const float4*)(xr + 2 * mm);
            ev[2 * i]     = v.x;  od[2 * i]     = v.y;
            ev[2 * i + 1] = v.z;  od[2 * i + 1] = v.w;
        }
        #pragma unroll
        for (int j = 0; j < 16; ++j) {
            float ao = 0.f, ae = 0.f;
            #pragma unroll
            for (int k = 0; k < 8; ++k) {
                ao = fmaf(wv8[k], ev[j + 8 - k], ao);
                ae = fmaf(sf[k],  od[j + 8 - k], ae);
            }
            buf[SW(c0 + j)] = od[j + 8] - ao;                // approx_1
            float d = hthr(ev[j + 8] - ae, a, bp, bm);
            loss += fabsf(d);
            det0[p * 16 + j] = d;
        }
    }
    if (lane == 0) {                               // stash det0[0..6] for halo
        #pragma unroll
        for (int k = 0; k < 7; ++k) wb[wv_id][k] = det0[k];
    }
    __syncthreads();

    // ---------- forward levels 1..4 (all threads; det_l -> LDS [M:2M)) ----------
    ldf_fwd(scaling, scaling_rec, 1, sf, wv8); fwd_level<16, false>(buf, 16384, tid, sf, wv8, a, bp, bm, loss);
    ldf_fwd(scaling, scaling_rec, 2, sf, wv8); fwd_level< 8, false>(buf,  8192, tid, sf, wv8, a, bp, bm, loss);
    ldf_fwd(scaling, scaling_rec, 3, sf, wv8); fwd_level< 4, false>(buf,  4096, tid, sf, wv8, a, bp, bm, loss);
    ldf_fwd(scaling, scaling_rec, 4, sf, wv8); fwd_level< 2, false>(buf,  2048, tid, sf, wv8, a, bp, bm, loss);

    // ---------- deep levels 5..9 + final threshold + inverse 9..5:
    //            single wave, no block barriers ----------
    if (wv_id == 0) {
        ldf_fwd(scaling, scaling_rec, 5, sf, wv8); fwd_level<16, true>(buf, 1024, lane, sf, wv8, a, bp, bm, loss);
        ldf_fwd(scaling, scaling_rec, 6, sf, wv8); fwd_level< 8, true>(buf,  512, lane, sf, wv8, a, bp, bm, loss);
        ldf_fwd(scaling, scaling_rec, 7, sf, wv8); fwd_level< 4, true>(buf,  256, lane, sf, wv8, a, bp, bm, loss);
        ldf_fwd(scaling, scaling_rec, 8, sf, wv8); fwd_level< 2, true>(buf,  128, lane, sf, wv8, a, bp, bm, loss);
        ldf_fwd(scaling, scaling_rec, 9, sf, wv8); fwd_level< 1, true>(buf,   64, lane, sf, wv8, a, bp, bm, loss);

        // threshold approx_10 (filtered[-1]); same-lane read/write, no sync
        float v = buf[SW(lane)];
        float f = hthr(v, a, bp, bm);
        loss += fabsf(f);
        buf[SW(lane)] = f;
        wave_sync();                               // cross-lane RAW for rec stage

        ldf_rec(scaling, scaling_rec, 9, sf, wv8); rec_level< 1, true>(buf,   64, lane, sf, wv8);
        ldf_rec(scaling, scaling_rec, 8, sf, wv8); rec_level< 2, true>(buf,  128, lane, sf, wv8);
        ldf_rec(scaling, scaling_rec, 7, sf, wv8); rec_level< 4, true>(buf,  256, lane, sf, wv8);
        ldf_rec(scaling, scaling_rec, 6, sf, wv8); rec_level< 8, true>(buf,  512, lane, sf, wv8);
        ldf_rec(scaling, scaling_rec, 5, sf, wv8); rec_level<16, true>(buf, 1024, lane, sf, wv8);
    }

    // ---------- reg_loss reduction (its barrier doubles as the post-deep sync) ----------
    {
        float l = loss;
        #pragma unroll
        for (int off = 32; off > 0; off >>= 1) l += __shfl_down(l, off, 64);
        if (lane == 0) lossbuf[wv_id] = l;
    }
    __syncthreads();
    if (tid == 0) {
        float s = 0.f;
        #pragma unroll
        for (int w = 0; w < 16; ++w) s += lossbuf[w];
        atomicAdd(out + LOSS_IDX, s);
    }

    // ---------- inverse levels 4..1 (all threads) ----------
    ldf_rec(scaling, scaling_rec, 4, sf, wv8); rec_level< 2, false>(buf,  2048, tid, sf, wv8);
    ldf_rec(scaling, scaling_rec, 3, sf, wv8); rec_level< 4, false>(buf,  4096, tid, sf, wv8);
    ldf_rec(scaling, scaling_rec, 2, sf, wv8); rec_level< 8, false>(buf,  8192, tid, sf, wv8);
    ldf_rec(scaling, scaling_rec, 1, sf, wv8); rec_level<16, false>(buf, 16384, tid, sf, wv8);

    // ---------- inverse level 0: approx_1 (LDS) + det_0 (regs, shfl halo)
    //            -> out (global float4). No barriers needed.
    //            det accessed via compile-time indices (no dt[] copy). ----------
    {
        ldf_rec(scaling, scaling_rec, 0, sf, wv8);
        float h[7];                                // neighbor thread's det0[0..6]
        #pragma unroll
        for (int k = 0; k < 7; ++k) h[k] = __shfl(det0[k], (lane + 1) & 63, 64);
        if (lane == 63) {
            #pragma unroll
            for (int k = 0; k < 7; ++k) h[k] = wb[(wv_id + 1) & 15][k];
        }
        #pragma unroll
        for (int p = 0; p < 2; ++p) {
            const int c0 = tid * 32 + p * 16;
            float od[23];
            #pragma unroll
            for (int j = 0; j < 23; ++j) od[j] = buf[SW((c0 + j) & 32767)];
            #pragma unroll
            for (int i = 0; i < 8; ++i) {
                float e2[2], o2[2];
                #pragma unroll
                for (int q = 0; q < 2; ++q) {
                    const int j = 2 * i + q;
                    float ae = 0.f, ao = 0.f;
                    #pragma unroll
                    for (int k = 0; k < 8; ++k) {
                        const int di = p * 16 + j + k;         // compile-time
                        float dv = (di < 32) ? det0[di] : h[di - 32];
                        ae = fmaf(sf[k],  od[j + k], ae);
                        ao = fmaf(wv8[k], dv, ao);
                    }
                    const int d0i = p * 16 + j;
                    float dvj = (d0i < 32) ? det0[d0i] : h[d0i - 32];
                    e2[q] = dvj + ae;              // even_rest
                    o2[q] = od[j] + ao;            // odd_rest
                }
                float4 o4 = make_float4(e2[0], o2[0], e2[1], o2[1]);
                *(float4*)(outr + 2 * (c0 + 2 * i)) = o4;
            }
        }
    }
}

extern "C" void kernel_launch(void* const* d_in, const int* in_sizes, int n_in,
                              void* d_out, int out_size, void* d_ws, size_t ws_size,
                              hipStream_t stream) {
    const float* x           = (const float*)d_in[0];
    const float* scaling     = (const float*)d_in[1];
    const float* scaling_rec = (const float*)d_in[2];
    const float* p_alpha     = (const float*)d_in[3];
    const float* p_bp        = (const float*)d_in[4];
    const float* p_bm        = (const float*)d_in[5];
    float* out = (float*)d_out;

    // zero the loss accumulator each launch (graph-capture safe)
    hipMemsetAsync(out + LOSS_IDX, 0, sizeof(float), stream);

    wavelet_vcycle_kernel<<<dim3(NROWS), dim3(TPB), 32768 * sizeof(float), stream>>>(
        x, scaling, scaling_rec, p_alpha, p_bp, p_bm, out);
}

// Round 4
// 96.828 us; speedup vs baseline: 1.0336x; 1.0336x over previous
//
#include <hip/hip_runtime.h>

#define NROWS 256
#define ROWLEN 65536
#define TPB 1024
#define LOSS_IDX ((size_t)NROWS * (size_t)ROWLEN)

// XOR swizzle: bijective involution within each 1024-float block; spreads the
// stride-2C chunked accesses across banks. Applied to EVERY access of buf[].
__device__ __forceinline__ int SW(int i) { return i ^ ((i >> 5) & 31); }

__device__ __forceinline__ float sigm(float z) { return 1.0f / (1.0f + __expf(-z)); }

__device__ __forceinline__ float hthr(float v, float a, float bp, float bm) {
    return v * (sigm(a * (v - bp)) + sigm(-a * (v + bm)));
}

// Intra-wave "barrier": compiler fence + lgkmcnt drain. Valid only when the
// producing and consuming lanes are in the SAME wave (deep levels, tid<64).
__device__ __forceinline__ void wave_sync() {
    __builtin_amdgcn_wave_barrier();
    __threadfence_block();
    __builtin_amdgcn_wave_barrier();
}

__device__ __forceinline__ void ldf_fwd(const float* sc, const float* rec, int lvl,
                                        float* sf, float* wv) {
    #pragma unroll
    for (int i = 0; i < 8; ++i) sf[i] = sc[lvl * 8 + i];
    #pragma unroll
    for (int i = 0; i < 8; ++i) {
        float r = rec[lvl * 8 + 7 - i];
        wv[i] = (i & 1) ? -r : r;            // _compute_wavelet
    }
}

__device__ __forceinline__ void ldf_rec(const float* sc, const float* rec, int lvl,
                                        float* sf, float* ws) {
    #pragma unroll
    for (int i = 0; i < 8; ++i) sf[i] = sc[lvl * 8 + i];
    #pragma unroll
    for (int i = 0; i < 8; ++i) {
        float r = rec[lvl * 8 + 7 - i];
        ws[i] = (i & 1) ? r : -r;            // _compute_wavelet_synthesis
    }
}

// Forward lifting level, fully in LDS: approx buf[0:2M) -> approx buf[0:M),
// thresholded detail -> buf[M:2M). Register-staged halo breaks the WAR.
template<int C, bool WAVE>
__device__ __forceinline__ void fwd_level(float* __restrict__ buf, int M, int tid,
                                          const float* sf, const float* wv,
                                          float a, float bp, float bm, float& loss)
{
    const int c0 = tid * C;          // C == M / nthreads exactly -> all active
    float ev[C + 7], od[C + 7];
    #pragma unroll
    for (int j = 0; j < C + 7; ++j) {
        int m = (c0 - 7 + j) & (M - 1);
        ev[j] = buf[SW(2 * m)];
        od[j] = buf[SW(2 * m + 1)];
    }
    if constexpr (WAVE) wave_sync(); else __syncthreads();
    #pragma unroll
    for (int j = 0; j < C; ++j) {
        float ao = 0.f, ae = 0.f;
        #pragma unroll
        for (int k = 0; k < 8; ++k) {
            ao = fmaf(wv[k], ev[j + 7 - k], ao);   // conv(even, wav)[n]
            ae = fmaf(sf[k], od[j + 7 - k], ae);   // conv(odd, scaling)[n]
        }
        int n = c0 + j;
        buf[SW(n)] = od[j + 7] - ao;               // odd_u -> next approx
        float d = hthr(ev[j + 7] - ae, a, bp, bm); // threshold(even_u)
        loss += fabsf(d);
        buf[SW(M + n)] = d;                        // det_l nests at [M:2M)
    }
    if constexpr (WAVE) wave_sync(); else __syncthreads();
}

// Inverse lifting level, fully in LDS: approx buf[0:M) + det buf[M:2M)
// -> buf[0:2M) interleaved [even_rest, odd_rest]. Register-staged.
template<int C, bool WAVE>
__device__ __forceinline__ void rec_level(float* __restrict__ buf, int M, int tid,
                                          const float* sf, const float* ws)
{
    const int c0 = tid * C;
    float od[C + 7], dt[C + 7];
    #pragma unroll
    for (int j = 0; j < C + 7; ++j) {
        int m = (c0 + j) & (M - 1);
        od[j] = buf[SW(m)];
        dt[j] = buf[SW(M + m)];
    }
    if constexpr (WAVE) wave_sync(); else __syncthreads();
    #pragma unroll
    for (int j = 0; j < C; ++j) {
        float ae = 0.f, ao = 0.f;
        #pragma unroll
        for (int k = 0; k < 8; ++k) {
            ae = fmaf(sf[k], od[j + k], ae);   // corr(odd, scaling)[n]
            ao = fmaf(ws[k], dt[j + k], ao);   // corr(even, ws)[n]
        }
        int n = c0 + j;
        buf[SW(2 * n)]     = dt[j] + ae;       // even_rest
        buf[SW(2 * n + 1)] = od[j] + ao;       // odd_rest
    }
    if constexpr (WAVE) wave_sync(); else __syncthreads();
}

// amdgpu_waves_per_eu(4,4): 128 KiB dynamic LDS caps us at 1 block/CU =
// 16 waves = 4 waves/EU, but the compiler can't see dynamic LDS size and
// by default targets 8 waves/EU (64-VGPR budget), spilling ~40 floats/thread
// to scratch for occupancy that can never materialize. Pinning min=max=4
// grants the full 512/4 = 128-VGPR budget -> no spills.
__global__ __launch_bounds__(TPB)
__attribute__((amdgpu_waves_per_eu(4, 4)))
void wavelet_vcycle_kernel(
    const float* __restrict__ x, const float* __restrict__ scaling,
    const float* __restrict__ scaling_rec, const float* __restrict__ pa,
    const float* __restrict__ pbp, const float* __restrict__ pbm,
    float* __restrict__ out)
{
    extern __shared__ float buf[];                 // 32768 floats = 128 KiB
    __shared__ float wb[16][8];                    // wave-boundary det0 halo
    __shared__ float lossbuf[16];
    const int tid  = threadIdx.x;
    const int lane = tid & 63;
    const int wv_id = tid >> 6;
    const int row = blockIdx.x;
    const float* xr = x + (size_t)row * ROWLEN;
    float* outr = out + (size_t)row * ROWLEN;
    const float a = pa[0], bp = pbp[0], bm = pbm[0];
    float loss = 0.f;
    float sf[8], wv8[8];
    float det0[32];                                // level-0 details live here

    // ---------- forward level 0: x (global, reg-staged float4) -> approx_1 (LDS)
    //            det_0 -> registers. Two passes of C=16. ----------
    ldf_fwd(scaling, scaling_rec, 0, sf, wv8);
    #pragma unroll
    for (int p = 0; p < 2; ++p) {
        const int c0 = tid * 32 + p * 16;
        float ev[24], od[24];
        #pragma unroll
        for (int i = 0; i < 12; ++i) {
            int mm = (c0 - 8 + 2 * i) & 32767;     // mm even -> no intra-vec wrap
            float4 v = *(const float4*)(xr + 2 * mm);
            ev[2 * i]     = v.x;  od[2 * i]     = v.y;
            ev[2 * i + 1] = v.z;  od[2 * i + 1] = v.w;
        }
        #pragma unroll
        for (int j = 0; j < 16; ++j) {
            float ao = 0.f, ae = 0.f;
            #pragma unroll
            for (int k = 0; k < 8; ++k) {
                ao = fmaf(wv8[k], ev[j + 8 - k], ao);
                ae = fmaf(sf[k],  od[j + 8 - k], ae);
            }
            buf[SW(c0 + j)] = od[j + 8] - ao;                // approx_1
            float d = hthr(ev[j + 8] - ae, a, bp, bm);
            loss += fabsf(d);
            det0[p * 16 + j] = d;
        }
    }
    if (lane == 0) {                               // stash det0[0..6] for halo
        #pragma unroll
        for (int k = 0; k < 7; ++k) wb[wv_id][k] = det0[k];
    }
    __syncthreads();

    // ---------- forward levels 1..4 (all threads; det_l -> LDS [M:2M)) ----------
    ldf_fwd(scaling, scaling_rec, 1, sf, wv8); fwd_level<16, false>(buf, 16384, tid, sf, wv8, a, bp, bm, loss);
    ldf_fwd(scaling, scaling_rec, 2, sf, wv8); fwd_level< 8, false>(buf,  8192, tid, sf, wv8, a, bp, bm, loss);
    ldf_fwd(scaling, scaling_rec, 3, sf, wv8); fwd_level< 4, false>(buf,  4096, tid, sf, wv8, a, bp, bm, loss);
    ldf_fwd(scaling, scaling_rec, 4, sf, wv8); fwd_level< 2, false>(buf,  2048, tid, sf, wv8, a, bp, bm, loss);

    // ---------- deep levels 5..9 + final threshold + inverse 9..5:
    //            single wave, no block barriers ----------
    if (wv_id == 0) {
        ldf_fwd(scaling, scaling_rec, 5, sf, wv8); fwd_level<16, true>(buf, 1024, lane, sf, wv8, a, bp, bm, loss);
        ldf_fwd(scaling, scaling_rec, 6, sf, wv8); fwd_level< 8, true>(buf,  512, lane, sf, wv8, a, bp, bm, loss);
        ldf_fwd(scaling, scaling_rec, 7, sf, wv8); fwd_level< 4, true>(buf,  256, lane, sf, wv8, a, bp, bm, loss);
        ldf_fwd(scaling, scaling_rec, 8, sf, wv8); fwd_level< 2, true>(buf,  128, lane, sf, wv8, a, bp, bm, loss);
        ldf_fwd(scaling, scaling_rec, 9, sf, wv8); fwd_level< 1, true>(buf,   64, lane, sf, wv8, a, bp, bm, loss);

        // threshold approx_10 (filtered[-1]); same-lane read/write, no sync
        float v = buf[SW(lane)];
        float f = hthr(v, a, bp, bm);
        loss += fabsf(f);
        buf[SW(lane)] = f;
        wave_sync();                               // cross-lane RAW for rec stage

        ldf_rec(scaling, scaling_rec, 9, sf, wv8); rec_level< 1, true>(buf,   64, lane, sf, wv8);
        ldf_rec(scaling, scaling_rec, 8, sf, wv8); rec_level< 2, true>(buf,  128, lane, sf, wv8);
        ldf_rec(scaling, scaling_rec, 7, sf, wv8); rec_level< 4, true>(buf,  256, lane, sf, wv8);
        ldf_rec(scaling, scaling_rec, 6, sf, wv8); rec_level< 8, true>(buf,  512, lane, sf, wv8);
        ldf_rec(scaling, scaling_rec, 5, sf, wv8); rec_level<16, true>(buf, 1024, lane, sf, wv8);
    }

    // ---------- reg_loss reduction (its barrier doubles as the post-deep sync) ----------
    {
        float l = loss;
        #pragma unroll
        for (int off = 32; off > 0; off >>= 1) l += __shfl_down(l, off, 64);
        if (lane == 0) lossbuf[wv_id] = l;
    }
    __syncthreads();
    if (tid == 0) {
        float s = 0.f;
        #pragma unroll
        for (int w = 0; w < 16; ++w) s += lossbuf[w];
        atomicAdd(out + LOSS_IDX, s);
    }

    // ---------- inverse levels 4..1 (all threads) ----------
    ldf_rec(scaling, scaling_rec, 4, sf, wv8); rec_level< 2, false>(buf,  2048, tid, sf, wv8);
    ldf_rec(scaling, scaling_rec, 3, sf, wv8); rec_level< 4, false>(buf,  4096, tid, sf, wv8);
    ldf_rec(scaling, scaling_rec, 2, sf, wv8); rec_level< 8, false>(buf,  8192, tid, sf, wv8);
    ldf_rec(scaling, scaling_rec, 1, sf, wv8); rec_level<16, false>(buf, 16384, tid, sf, wv8);

    // ---------- inverse level 0: approx_1 (LDS) + det_0 (regs, shfl halo)
    //            -> out (global float4). No barriers needed.
    //            det accessed via compile-time indices (no dt[] copy). ----------
    {
        ldf_rec(scaling, scaling_rec, 0, sf, wv8);
        float h[7];                                // neighbor thread's det0[0..6]
        #pragma unroll
        for (int k = 0; k < 7; ++k) h[k] = __shfl(det0[k], (lane + 1) & 63, 64);
        if (lane == 63) {
            #pragma unroll
            for (int k = 0; k < 7; ++k) h[k] = wb[(wv_id + 1) & 15][k];
        }
        #pragma unroll
        for (int p = 0; p < 2; ++p) {
            const int c0 = tid * 32 + p * 16;
            float od[23];
            #pragma unroll
            for (int j = 0; j < 23; ++j) od[j] = buf[SW((c0 + j) & 32767)];
            #pragma unroll
            for (int i = 0; i < 8; ++i) {
                float e2[2], o2[2];
                #pragma unroll
                for (int q = 0; q < 2; ++q) {
                    const int j = 2 * i + q;
                    float ae = 0.f, ao = 0.f;
                    #pragma unroll
                    for (int k = 0; k < 8; ++k) {
                        const int di = p * 16 + j + k;         // compile-time
                        float dv = (di < 32) ? det0[di] : h[di - 32];
                        ae = fmaf(sf[k],  od[j + k], ae);
                        ao = fmaf(wv8[k], dv, ao);
                    }
                    const int d0i = p * 16 + j;
                    float dvj = (d0i < 32) ? det0[d0i] : h[d0i - 32];
                    e2[q] = dvj + ae;              // even_rest
                    o2[q] = od[j] + ao;            // odd_rest
                }
                float4 o4 = make_float4(e2[0], o2[0], e2[1], o2[1]);
                *(float4*)(outr + 2 * (c0 + 2 * i)) = o4;
            }
        }
    }
}

extern "C" void kernel_launch(void* const* d_in, const int* in_sizes, int n_in,
                              void* d_out, int out_size, void* d_ws, size_t ws_size,
                              hipStream_t stream) {
    const float* x           = (const float*)d_in[0];
    const float* scaling     = (const float*)d_in[1];
    const float* scaling_rec = (const float*)d_in[2];
    const float* p_alpha     = (const float*)d_in[3];
    const float* p_bp        = (const float*)d_in[4];
    const float* p_bm        = (const float*)d_in[5];
    float* out = (float*)d_out;

    // zero the loss accumulator each launch (graph-capture safe)
    hipMemsetAsync(out + LOSS_IDX, 0, sizeof(float), stream);

    wavelet_vcycle_kernel<<<dim3(NROWS), dim3(TPB), 32768 * sizeof(float), stream>>>(
        x, scaling, scaling_rec, p_alpha, p_bp, p_bm, out);
}